// Round 10
// baseline (405.456 us; speedup 1.0000x reference)
//
#include <hip/hip_runtime.h>
#include <hip/hip_bf16.h>

// MLA prefill: B=1, T=2048, C=2048, H=16, DN=128, DR=64, DV=128, QKD=192,
// RQ=1536, RKV=512. Inputs f32, output f32.
// Round 16 (= round 15 resubmitted -- bench infra failed, kernel re-audited:
// no deadlock (uniform barriers, exact vmcnt FIFO counts), no OOB):
//  * GEMM: 3-buffer software pipeline with RAW s_barrier + COUNTED vmcnt
//    (T3/T4 minimum recipe). Stage tile t+2 at iter t; s_waitcnt vmcnt(8/4/0)
//    -- never drains in steady state, so L2/HBM latency (300-900cy) gets ~2
//    iterations to land instead of sitting on every K-step's critical path.
//  * attn unchanged from round 14 (8-wave split-s groups, 59.3us).

#define T_DIM 2048
#define H_DIM 16
#define SCALE_F 0.07216878364870322f   // 192^-0.5
#define EPS_F 1e-6f
#define NEG_INF (-3.402823466e38f)

typedef __attribute__((ext_vector_type(8))) short short8;
typedef __attribute__((ext_vector_type(4))) float f32x4;
typedef __attribute__((address_space(3))) char lds_char;
typedef const __attribute__((address_space(1))) char glb_char;

__device__ inline void st_out(float* p, float v) { *p = v; }
__device__ inline void st_out(__hip_bfloat16* p, float v) { *p = __float2bfloat16(v); }

// ---------------- generic f32 -> bf16 cast ----------------------------------
__global__ void cast_bf16_kernel(const float* __restrict__ src,
                                 __hip_bfloat16* __restrict__ dst,
                                 int n4_src, int n4_dst) {
    int i = blockIdx.x * 256 + threadIdx.x;
    if (i >= n4_dst) return;
    float4 v = make_float4(0.f, 0.f, 0.f, 0.f);
    if (i < n4_src) v = ((const float4*)src)[i];
    dst[4 * i + 0] = __float2bfloat16(v.x);
    dst[4 * i + 1] = __float2bfloat16(v.y);
    dst[4 * i + 2] = __float2bfloat16(v.z);
    dst[4 * i + 3] = __float2bfloat16(v.w);
}

// ---------------- megacast: x, wq_a+wkv_a(pad)->A1, wq_b->A2, biases --------
__global__ void megacast_kernel(const float* __restrict__ x,
                                const float* __restrict__ wq_a,
                                const float* __restrict__ wkv_a,
                                const float* __restrict__ wq_b,
                                const float* __restrict__ bq_a,
                                const float* __restrict__ bkv_a,
                                __hip_bfloat16* __restrict__ x_bf,
                                __hip_bfloat16* __restrict__ A1,
                                __hip_bfloat16* __restrict__ A2,
                                float* __restrict__ bias_ab) {
    const int i = blockIdx.x * 256 + threadIdx.x;
    float4 v = make_float4(0.f, 0.f, 0.f, 0.f);
    __hip_bfloat16* dst;
    if (i < 1048576) {
        v = ((const float4*)x)[i];            dst = x_bf + 4 * (size_t)i;
    } else if (i < 1835008) {
        int k = i - 1048576;
        v = ((const float4*)wq_a)[k];         dst = A1 + 4 * (size_t)k;
    } else if (i < 2162688) {
        int k = i - 1835008;
        if (k < 294912) v = ((const float4*)wkv_a)[k];
        dst = A1 + (size_t)(786432 + k) * 4;
    } else if (i < 3342336) {
        int k = i - 2162688;
        v = ((const float4*)wq_b)[k];         dst = A2 + 4 * (size_t)k;
    } else if (i < 3342880) {
        int k = i - 3342336;                  // bias granule
        float4 b = make_float4(0.f, 0.f, 0.f, 0.f);
        if (k < 384) b = ((const float4*)bq_a)[k];
        else if (k < 528) b = ((const float4*)bkv_a)[k - 384];
        ((float4*)bias_ab)[k] = b;
        return;
    } else return;
    dst[0] = __float2bfloat16(v.x);
    dst[1] = __float2bfloat16(v.y);
    dst[2] = __float2bfloat16(v.z);
    dst[3] = __float2bfloat16(v.w);
}

// ---------------- MFMA GEMM: C[M,N] = A[M,K] @ W[N,K]^T + bias[N] -----------
// 512 threads / 8 waves; wave = 32x64 quadrant; BK=64. 3-buffer pipeline:
// iter t stages tile t+2, then counted s_waitcnt vmcnt(8) (t+1,t+2 in flight
// = 8 loads/wave) + raw s_barrier, ds_read+MFMA on buf[t%3], raw s_barrier.
// Buffer rotation safe: buf[(t+2)%3]'s previous readers (iter t-1) are behind
// the end-of-iter barrier. Source-preswizzled global_load_lds + XOR ds_read
// (rule #21); bijective XCD remap; optional rope / split-output epilogue.
template <typename OT, bool ROPE>
__global__ __launch_bounds__(512) void gemm_mfma_kernel(
    const __hip_bfloat16* __restrict__ A, int lda,
    const __hip_bfloat16* __restrict__ W, int ldw,
    const float* __restrict__ bias,
    OT* __restrict__ C, int ldc,
    float* __restrict__ C2, int ldc2, int splitN, int K,
    const float* __restrict__ freqs) {
    __shared__ __hip_bfloat16 As[3][128 * 64];
    __shared__ __hip_bfloat16 Bs[3][128 * 64];
    const int tid = threadIdx.x;
    const int w = tid >> 6, lane = tid & 63, qd = lane >> 4, lx = lane & 15;

    // bijective XCD remap (m204)
    const int nwg = gridDim.x * gridDim.y;
    const int o = blockIdx.y * gridDim.x + blockIdx.x;
    const int qx = nwg >> 3, rx = nwg & 7;
    const int xcd = o & 7, idx = o >> 3;
    const int neu = (xcd < rx ? xcd * (qx + 1) : rx * (qx + 1) + (xcd - rx) * qx) + idx;
    const int rowB = (neu / gridDim.x) * 128, colB = (neu % gridDim.x) * 128;

    const int wr = (w >> 1) * 32, wc = (w & 1) * 64;

    f32x4 acc[2][4];
#pragma unroll
    for (int i = 0; i < 2; ++i)
#pragma unroll
        for (int j = 0; j < 4; ++j) acc[i][j] = (f32x4)(0.f);

    auto stage = [&](int buf, int k0) {
#pragma unroll
        for (int it = 0; it < 2; ++it) {
            const int g = tid + it * 512;              // 0..1023 granules
            const int row = g >> 3, s = g & 7;
            const int sc = (s ^ (row & 7)) * 8;        // pre-swizzled src col
            const __hip_bfloat16* ga = A + (size_t)(rowB + row) * lda + k0 + sc;
            __builtin_amdgcn_global_load_lds((glb_char*)ga,
                (lds_char*)((char*)&As[buf][0] + (size_t)g * 16), 16, 0, 0);
            const __hip_bfloat16* gb = W + (size_t)(colB + row) * ldw + k0 + sc;
            __builtin_amdgcn_global_load_lds((glb_char*)gb,
                (lds_char*)((char*)&Bs[buf][0] + (size_t)g * 16), 16, 0, 0);
        }
    };

    const int NT = K >> 6;            // K/64; >= 8 for all our shapes
    stage(0, 0);
    stage(1, 64);
    const int swz = (lx & 7) << 4;
    for (int t = 0; t < NT; ++t) {
        // stage t+2, then wait ONLY for tile t's loads (counted, never drain)
        if (t + 2 < NT) {
            stage((t + 2) % 3, (t + 2) * 64);
            asm volatile("s_waitcnt vmcnt(8)" ::: "memory");
        } else if (t + 1 < NT) {
            asm volatile("s_waitcnt vmcnt(4)" ::: "memory");
        } else {
            asm volatile("s_waitcnt vmcnt(0)" ::: "memory");
        }
        __builtin_amdgcn_s_barrier();          // all waves' tile-t loads landed
        __builtin_amdgcn_sched_barrier(0);

        const int cur = t % 3;
#pragma unroll
        for (int kk = 0; kk < 2; ++kk) {
            short8 a[2], b[4];
#pragma unroll
            for (int rt = 0; rt < 2; ++rt)
                a[rt] = *(const short8*)((char*)&As[cur][0]
                    + (size_t)(wr + rt * 16 + lx) * 128 + ((kk * 64 + qd * 16) ^ swz));
#pragma unroll
            for (int ct = 0; ct < 4; ++ct)
                b[ct] = *(const short8*)((char*)&Bs[cur][0]
                    + (size_t)(wc + ct * 16 + lx) * 128 + ((kk * 64 + qd * 16) ^ swz));
#pragma unroll
            for (int rt = 0; rt < 2; ++rt)
#pragma unroll
                for (int ct = 0; ct < 4; ++ct)
                    acc[rt][ct] = __builtin_amdgcn_mfma_f32_16x16x32_bf16(a[rt], b[ct], acc[rt][ct], 0, 0, 0);
        }
        __builtin_amdgcn_s_barrier();          // readers done: buf[t%3] may be re-staged
        __builtin_amdgcn_sched_barrier(0);
    }

    // epilogue: C/D layout col=lane&15, row=4*qd+reg
    const bool second = (C2 != nullptr) && (colB >= splitN);
#pragma unroll
    for (int rt = 0; rt < 2; ++rt)
#pragma unroll
        for (int j = 0; j < 4; ++j) {
            const int row = rowB + wr + rt * 16 + 4 * qd + j;
#pragma unroll
            for (int ct = 0; ct < 4; ++ct) {
                const int col = colB + wc + ct * 16 + lx;
                float v = acc[rt][ct][j] + bias[col];
                if constexpr (ROPE) {
                    const float pv = __shfl_xor(v, 1);   // partner col (col^1)
                    const int dm = col % 192;
                    if (dm >= 128) {
                        const int ii = (dm - 128) >> 1;
                        const float f = freqs[row * 32 + ii];
                        const float cc = cosf(f), ss = sinf(f);
                        v = (lane & 1) ? (pv * ss + v * cc)
                                       : (v * cc - pv * ss);
                    }
                }
                if (second) C2[(size_t)row * ldc2 + (col - splitN)] = v;
                else        st_out(&C[(size_t)row * ldc + col], v);
            }
        }
}

// ---------------- RMSNorm: f32 in -> bf16 out -------------------------------
__global__ void rmsnorm_kernel(const float* __restrict__ in, __hip_bfloat16* __restrict__ outp,
                               const float* __restrict__ w,
                               int D, int in_stride, int out_stride) {
    const int row = blockIdx.x;
    const float* p = in + (size_t)row * in_stride;
    __hip_bfloat16* o = outp + (size_t)row * out_stride;
    const int tid = threadIdx.x;  // 256
    float ss = 0.f;
    for (int i = tid; i < D; i += 256) { float v = p[i]; ss += v * v; }
    __shared__ float red[256];
    red[tid] = ss;
    __syncthreads();
    for (int off = 128; off > 0; off >>= 1) {
        if (tid < off) red[tid] += red[tid + off];
        __syncthreads();
    }
    const float scale = rsqrtf(red[0] / (float)D + EPS_F);
    for (int i = tid; i < D; i += 256)
        o[i] = __float2bfloat16(p[i] * scale * w[i]);
}

// ---------------- fused rmsnorm(kv_lat) + rope(k_pe) per row ----------------
__global__ void rmsnorm_rope_kv_kernel(const float* __restrict__ kvpe,
                                       __hip_bfloat16* __restrict__ kv_lat_bf,
                                       const float* __restrict__ w,
                                       const float* __restrict__ freqs,
                                       __hip_bfloat16* __restrict__ kpe) {
    const int row = blockIdx.x;
    const float* p = kvpe + (size_t)row * 640;
    const int tid = threadIdx.x;  // 256
    float v0 = p[tid], v1 = p[tid + 256];
    __shared__ float red[256];
    red[tid] = v0 * v0 + v1 * v1;
    __syncthreads();
    for (int off = 128; off > 0; off >>= 1) {
        if (tid < off) red[tid] += red[tid + off];
        __syncthreads();
    }
    const float scale = rsqrtf(red[0] / 512.f + EPS_F);
    __hip_bfloat16* o = kv_lat_bf + (size_t)row * 512;
    o[tid]       = __float2bfloat16(v0 * scale * w[tid]);
    o[tid + 256] = __float2bfloat16(v1 * scale * w[tid + 256]);
    if (tid < 32) {
        const float f = freqs[row * 32 + tid];
        const float c = cosf(f), s = sinf(f);
        const float xr = p[512 + 2 * tid], xi = p[512 + 2 * tid + 1];
        kpe[(size_t)row * 64 + 2 * tid]     = __float2bfloat16(xr * c - xi * s);
        kpe[(size_t)row * 64 + 2 * tid + 1] = __float2bfloat16(xr * s + xi * c);
    }
}

// ---------------- pack V transposed: kvb_bf (T,H*256) -> vT (H,128,T) -------
__global__ void pack_vT_kernel(const __hip_bfloat16* __restrict__ kvb,
                               __hip_bfloat16* __restrict__ vT) {
    const int t0 = blockIdx.x * 64;
    const int h = blockIdx.y;
    const int tid = threadIdx.x;
    __shared__ __hip_bfloat16 Ls[64][136];
#pragma unroll
    for (int it = 0; it < 4; ++it) {
        int c = tid + 256 * it;
        int i = c >> 4, part = c & 15;
        *(uint4*)&Ls[i][part * 8] =
            *(const uint4*)(kvb + (size_t)(t0 + i) * 4096 + h * 256 + 128 + part * 8);
    }
    __syncthreads();
#pragma unroll
    for (int it = 0; it < 32; ++it) {
        int c = tid + 256 * it;
        int d = c >> 6, i = c & 63;
        vT[((size_t)(h * 128 + d)) * 2048 + t0 + i] = Ls[i][d];
    }
}

// ---------------- MFMA flash attention: 8-wave split-s groups ---------------
// (unchanged from round 14: 59.3us measured)
__global__ __launch_bounds__(512) void attn_mfma_kernel(
    const __hip_bfloat16* __restrict__ q,
    const __hip_bfloat16* __restrict__ kv,
    const __hip_bfloat16* __restrict__ kpe,
    const __hip_bfloat16* __restrict__ vT,
    __hip_bfloat16* __restrict__ y) {
    const int o = blockIdx.x;             // 512 = 8 XCD * 64
    const int xcd = o & 7, slot = o >> 3;
    const int h  = xcd * 2 + (slot & 1);  // each XCD owns 2 heads
    const int qt = 31 - (slot >> 1);      // longest blocks first
    const int q0 = qt * 64;
    const int NT2 = (qt >> 1) + 1;        // pairs of 64-key tiles
    const int tid = threadIdx.x;
    const int w = tid >> 6, g = w >> 2, wl = w & 3;
    const int lane = tid & 63, qd = lane >> 4, lx = lane & 15;
    const int stid = tid & 255;           // staging id within group

    __shared__ __hip_bfloat16 KsB[2][64 * 192];   // per-group; 384B rows
    __shared__ __hip_bfloat16 VsB[2][128 * 64];   // per-group; 128B rows
    __shared__ __hip_bfloat16 Ps[8][16][72];

#define KS_ADDR(gg, row, boff) ((char*)&KsB[gg][0] + (size_t)(row) * 384 + ((boff) ^ (((row) & 7) << 4)))
#define VS_ADDR(gg, row, boff) ((char*)&VsB[gg][0] + (size_t)(row) * 128 + ((boff) ^ (((row) & 7) << 4)))

    short8 qf[6];
    {
        const __hip_bfloat16* qrow =
            q + (size_t)(q0 + 16 * wl + lx) * 3072 + h * 192 + qd * 8;
#pragma unroll
        for (int kc = 0; kc < 6; ++kc)
            qf[kc] = *(const short8*)(qrow + kc * 32);
    }

    f32x4 O[8];
#pragma unroll
    for (int i = 0; i < 8; ++i) O[i] = (f32x4)(0.f);
    float mrow[4], lrow[4];
#pragma unroll
    for (int j = 0; j < 4; ++j) { mrow[j] = NEG_INF; lrow[j] = 0.f; }

    const short8 vone = (short8)(short)0x3F80;   // bf16 1.0 splat

    // ---- prefetch state: 10 NAMED uint4 per thread (group-local tile) ----
    uint4 k0r, k1r, k2r, k3r, pe0r, pe1r, v0r, v1r, v2r, v3r;
    const __hip_bfloat16* kvh = kv + h * 256;
    const __hip_bfloat16* vTh = vT + (size_t)h * 128 * 2048;

#define PREFETCH(S0)                                                               \
    do {                                                                           \
        const size_t kk_ = (size_t)(S0) + (stid >> 4);                             \
        const int kp_ = (stid & 15) * 8;                                           \
        k0r = *(const uint4*)(kvh + (kk_ +  0) * 4096 + kp_);                      \
        k1r = *(const uint4*)(kvh + (kk_ + 16) * 4096 + kp_);                      \
        k2r = *(const uint4*)(kvh + (kk_ + 32) * 4096 + kp_);                      \
        k3r = *(const uint4*)(kvh + (kk_ + 48) * 4096 + kp_);                      \
        const size_t pk_ = (size_t)(S0) + (stid >> 3);                             \
        const int pp_ = (stid & 7) * 8;                                            \
        pe0r = *(const uint4*)(kpe + (pk_ +  0) * 64 + pp_);                       \
        pe1r = *(const uint4*)(kpe + (pk_ + 32) * 64 + pp_);                       \
        const __hip_bfloat16* vp_ = vTh + ((size_t)(stid >> 3)) * 2048 + (S0) + pp_;\
        v0r = *(const uint4*)(vp_ + 0 * 65536);                                    \
        v1r = *(const uint4*)(vp_ + 1 * 65536);                                    \
        v2r = *(const uint4*)(vp_ + 2 * 65536);                                    \
        v3r = *(const uint4*)(vp_ + 3 * 65536);                                    \
    } while (0)

// one 64-key online-softmax + PV pass over group buffer GG, keys at S0P
#define COMPUTE64(S0P, GG)                                                         \
    do {                                                                           \
        f32x4 S[4];                                                                \
        _Pragma("unroll")                                                          \
        for (int nt = 0; nt < 4; ++nt) S[nt] = (f32x4)(0.f);                       \
        __builtin_amdgcn_s_setprio(1);                                             \
        _Pragma("unroll")                                                          \
        for (int kc = 0; kc < 6; ++kc) {                                           \
            short8 a = qf[kc];                                                     \
            _Pragma("unroll")                                                      \
            for (int nt = 0; nt < 4; ++nt) {                                       \
                short8 b = *(const short8*)KS_ADDR(GG, nt * 16 + lx,               \
                                                   kc * 64 + qd * 16);             \
                S[nt] = __builtin_amdgcn_mfma_f32_16x16x32_bf16(a, b, S[nt], 0, 0, 0); \
            }                                                                      \
        }                                                                          \
        __builtin_amdgcn_s_setprio(0);                                             \
        float sv[4][4];                                                            \
        _Pragma("unroll")                                                          \
        for (int nt = 0; nt < 4; ++nt) {                                           \
            int col = (S0P) + nt * 16 + lx;                                        \
            _Pragma("unroll")                                                      \
            for (int j = 0; j < 4; ++j) {                                          \
                int row = q0 + 16 * wl + 4 * qd + j;                               \
                float v = S[nt][j] * SCALE_F;                                      \
                sv[nt][j] = (col > row) ? NEG_INF : v;                             \
            }                                                                      \
        }                                                                          \
        float pmax[4];                                                             \
        _Pragma("unroll")                                                          \
        for (int j = 0; j < 4; ++j)                                                \
            pmax[j] = fmaxf(fmaxf(sv[0][j], sv[1][j]), fmaxf(sv[2][j], sv[3][j])); \
        const bool need = !__all((pmax[0] <= mrow[0] + 8.f) &&                     \
                                 (pmax[1] <= mrow[1] + 8.f) &&                     \
                                 (pmax[2] <= mrow[2] + 8.f) &&                     \
                                 (pmax[3] <= mrow[3] + 8.f));                      \
        if (need) {                                                                \
            float al[4];                                                           \
            _Pragma("unroll")                                                      \
            for (int j = 0; j < 4; ++j) {                                          \
                float rm = pmax[j];                                                \
                _Pragma("unroll")                                                  \
                for (int msk = 1; msk < 16; msk <<= 1)                             \
                    rm = fmaxf(rm, __shfl_xor(rm, msk));                           \
                const float mn = fmaxf(mrow[j], rm);                               \
                al[j] = __expf(mrow[j] - mn);                                      \
                mrow[j] = mn;                                                      \
                lrow[j] *= al[j];                                                  \
            }                                                                      \
            _Pragma("unroll")                                                      \
            for (int nt = 0; nt < 8; ++nt)                                         \
                _Pragma("unroll")                                                  \
                for (int j = 0; j < 4; ++j) O[nt][j] *= al[j];                     \
        }                                                                          \
        _Pragma("unroll")                                                          \
        for (int nt = 0; nt < 4; ++nt)                                             \
            _Pragma("unroll")                                                      \
            for (int j = 0; j < 4; ++j) {                                          \
                float pp = __expf(sv[nt][j] - mrow[j]);                            \
                Ps[w][4 * qd + j][nt * 16 + lx] = __float2bfloat16(pp);            \
            }                                                                      \
        asm volatile("s_waitcnt lgkmcnt(0)" ::: "memory");                         \
        f32x4 lacc = (f32x4)(0.f);                                                 \
        __builtin_amdgcn_s_setprio(1);                                             \
        _Pragma("unroll")                                                          \
        for (int kc2 = 0; kc2 < 2; ++kc2) {                                        \
            short8 pa = *(const short8*)&Ps[w][lx][kc2 * 32 + qd * 8];             \
            _Pragma("unroll")                                                      \
            for (int nt = 0; nt < 8; ++nt) {                                       \
                short8 vb = *(const short8*)VS_ADDR(GG, nt * 16 + lx,              \
                                                    kc2 * 64 + qd * 16);           \
                O[nt] = __builtin_amdgcn_mfma_f32_16x16x32_bf16(pa, vb, O[nt], 0, 0, 0); \
            }                                                                      \
            lacc = __builtin_amdgcn_mfma_f32_16x16x32_bf16(pa, vone, lacc, 0, 0, 0); \
        }                                                                          \
        __builtin_amdgcn_s_setprio(0);                                             \
        _Pragma("unroll")                                                          \
        for (int j = 0; j < 4; ++j) lrow[j] += lacc[j];                            \
    } while (0)

    if (g <= qt) PREFETCH(g * 64);

    for (int t2 = 0; t2 < NT2; ++t2) {
        const int t = 2 * t2 + g;
        const bool act = (t <= qt);        // group-uniform (wave-uniform)
        __syncthreads();   // all waves done reading their group buffer
        if (act) {
            const int kr_ = stid >> 4, kb_ = (stid & 15) * 16;
            *(uint4*)KS_ADDR(g, kr_ +  0, kb_) = k0r;
            *(uint4*)KS_ADDR(g, kr_ + 16, kb_) = k1r;
            *(uint4*)KS_ADDR(g, kr_ + 32, kb_) = k2r;
            *(uint4*)KS_ADDR(g, kr_ + 48, kb_) = k3r;
            const int pr_ = stid >> 3, pb_ = (stid & 7) * 16;
            *(uint4*)KS_ADDR(g, pr_ +  0, 256 + pb_) = pe0r;
            *(uint4*)KS_ADDR(g, pr_ + 32, 256 + pb_) = pe1r;
            *(uint4*)VS_ADDR(g, pr_ +  0, pb_) = v0r;
            *(uint4*)VS_ADDR(g, pr_ + 32, pb_) = v1r;
            *(uint4*)VS_ADDR(g, pr_ + 64, pb_) = v2r;
            *(uint4*)VS_ADDR(g, pr_ + 96, pb_) = v3r;
        }
        __syncthreads();   // tiles visible

        const int tn = 2 * (t2 + 1) + g;
        if (tn <= qt) PREFETCH(tn * 64);   // latency hides under compute

        if (act) COMPUTE64(t * 64, g);
    }
#undef PREFETCH
#undef COMPUTE64
#undef KS_ADDR
#undef VS_ADDR

    // ---- merge group 1 state into group 0, write y ----
    float* Osh = (float*)&KsB[0][0];       // 64 x 128 f32 (32 KB <= 48 KB)
    float* msh = (float*)&VsB[0][0];       // 64
    float* lsh = msh + 64;
    __syncthreads();                       // group 0 done reading LDS
    if (g == 1) {
#pragma unroll
        for (int j = 0; j < 4; ++j) {
            const int r = 16 * wl + 4 * qd + j;
            if (lx == 0) { msh[r] = mrow[j]; lsh[r] = lrow[j]; }
#pragma unroll
            for (int nt = 0; nt < 8; ++nt)
                Osh[r * 128 + nt * 16 + lx] = O[nt][j];
        }
    }
    __syncthreads();
    if (g == 0) {
#pragma unroll
        for (int j = 0; j < 4; ++j) {
            const int r = 16 * wl + 4 * qd + j;
            const float m1 = msh[r], l1 = lsh[r];
            const float M  = fmaxf(mrow[j], m1);
            const float a0 = __expf(mrow[j] - M);
            const float a1 = __expf(m1 - M);        // 0 when group 1 idle
            const float inv = 1.f / (lrow[j] * a0 + l1 * a1);
            const int t = q0 + r;
            __hip_bfloat16* yr = y + (size_t)t * 2048 + h * 128 + lx;
#pragma unroll
            for (int nt = 0; nt < 8; ++nt)
                yr[nt * 16] = __float2bfloat16(
                    (O[nt][j] * a0 + Osh[r * 128 + nt * 16 + lx] * a1) * inv);
        }
    }
}

extern "C" void kernel_launch(void* const* d_in, const int* in_sizes, int n_in,
                              void* d_out, int out_size, void* d_ws, size_t ws_size,
                              hipStream_t stream) {
    const float* x         = (const float*)d_in[0];
    const float* freqs     = (const float*)d_in[1];
    const float* wq_a      = (const float*)d_in[2];
    const float* bq_a      = (const float*)d_in[3];
    const float* q_norm_w  = (const float*)d_in[4];
    const float* wq_b      = (const float*)d_in[5];
    const float* bq_b      = (const float*)d_in[6];
    const float* wkv_a     = (const float*)d_in[7];
    const float* bkv_a     = (const float*)d_in[8];
    const float* kv_norm_w = (const float*)d_in[9];
    const float* wkv_b     = (const float*)d_in[10];
    const float* bkv_b     = (const float*)d_in[11];
    const float* wo        = (const float*)d_in[12];
    const float* bo        = (const float*)d_in[13];
    float* out = (float*)d_out;

    // Workspace layout (~74 MB).
    char* p = (char*)d_ws;
    float* q_lat = (float*)p;                        p += (size_t)2048 * 1536 * 4;  // later hosts yb_bf
    float* kvpe  = (float*)p;                        p += (size_t)2048 * 640 * 4;
    __hip_bfloat16* x_bf      = (__hip_bfloat16*)p;  p += (size_t)2048 * 2048 * 2;  // later hosts vT
    __hip_bfloat16* q_lat_bf  = (__hip_bfloat16*)p;  p += (size_t)2048 * 1536 * 2;
    __hip_bfloat16* qb_bf     = (__hip_bfloat16*)p;  p += (size_t)2048 * 3072 * 2;
    __hip_bfloat16* kv_lat_bf = (__hip_bfloat16*)p;  p += (size_t)2048 * 512 * 2;
    __hip_bfloat16* kvb_bf    = (__hip_bfloat16*)p;  p += (size_t)2048 * 4096 * 2;
    __hip_bfloat16* kpe_bf    = (__hip_bfloat16*)p;  p += (size_t)2048 * 64 * 2;
    __hip_bfloat16* A1        = (__hip_bfloat16*)p;  p += (size_t)3072 * 1536 * 2;  // weight arena (9.44 MB)
    float* bias_ab = (float*)p;                      p += (size_t)2176 * 4;
    __hip_bfloat16* vT    = x_bf;                    // alias: x_bf dead after G12
    __hip_bfloat16* yb_bf = (__hip_bfloat16*)q_lat;  // alias: q_lat dead after rmsnorm
    __hip_bfloat16* A2    = kvb_bf;                  // alias: wq_b lives cast..G3 < G4 write

    // 1. megacast: x, wq_a+wkv_a -> A1, wq_b -> A2, fused bias
    megacast_kernel<<<13059, 256, 0, stream>>>(x, wq_a, wkv_a, wq_b, bq_a, bkv_a,
                                               x_bf, A1, A2, bias_ab);
    // 2. GEMM 1+2 fused: [q_lat | kvpe] = x_bf @ A1^T + bias
    gemm_mfma_kernel<float, false><<<dim3(17, 16), 512, 0, stream>>>(
        x_bf, 2048, A1, 2048, bias_ab, q_lat, 1536, kvpe, 640, 1536, 2048, nullptr);
    // 3. wkv_b -> A1 (A1 free after G12)
    cast_bf16_kernel<<<2048, 256, 0, stream>>>(wkv_b, A1, 524288, 524288);
    // 4. rmsnorm q -> bf16
    rmsnorm_kernel<<<2048, 256, 0, stream>>>(q_lat, q_lat_bf, q_norm_w, 1536, 1536, 1536);
    // 5. GEMM 3 + fused rope_q: qb_bf = q_lat_bf @ wq_b^T + bq_b
    gemm_mfma_kernel<__hip_bfloat16, true><<<dim3(24, 16), 512, 0, stream>>>(
        q_lat_bf, 1536, A2, 1536, bq_b, qb_bf, 3072, nullptr, 0, 1 << 30, 1536, freqs);
    // 6. fused rmsnorm(kv) + rope(k_pe)
    rmsnorm_rope_kv_kernel<<<2048, 256, 0, stream>>>(kvpe, kv_lat_bf, kv_norm_w, freqs, kpe_bf);
    // 7. GEMM 4: kvb_bf = kv_lat_bf @ wkv_b^T + bkv_b
    gemm_mfma_kernel<__hip_bfloat16, false><<<dim3(32, 16), 512, 0, stream>>>(
        kv_lat_bf, 512, A1, 512, bkv_b, kvb_bf, 4096, nullptr, 0, 1 << 30, 512, nullptr);
    // 8. wo -> A1 (A1 free after G4)
    cast_bf16_kernel<<<4096, 256, 0, stream>>>(wo, A1, 1048576, 1048576);
    // 9. pack V^T
    pack_vT_kernel<<<dim3(32, 16), 256, 0, stream>>>(kvb_bf, vT);
    // 10. attention (512 threads: 2 split-s wave groups)
    attn_mfma_kernel<<<512, 512, 0, stream>>>(qb_bf, kvb_bf, kpe_bf, vT, yb_bf);
    // 11. GEMM 5: out = yb_bf @ wo^T + bo
    gemm_mfma_kernel<float, false><<<dim3(16, 16), 512, 0, stream>>>(
        yb_bf, 2048, A1, 2048, bo, out, 2048, nullptr, 0, 1 << 30, 2048, nullptr);
}

// Round 11
// 337.177 us; speedup vs baseline: 1.2025x; 1.2025x over previous
//
#include <hip/hip_runtime.h>
#include <hip/hip_bf16.h>

// MLA prefill: B=1, T=2048, C=2048, H=16, DN=128, DR=64, DV=128, QKD=192,
// RQ=1536, RKV=512. Inputs f32, output f32.
// Round 17:
//  * GEMM: 2-buffer counted-vmcnt pipeline. Round-10's 3-buffer version lost
//    2-blocks/CU co-residency (96KB LDS -> occupancy 14.9%) and pinned the
//    scheduler with sched_barrier(0) (known m141 regression) -- both fixed:
//    64KB LDS (2 blocks/CU), stage t+1 at top of iter t, s_waitcnt vmcnt(4)
//    (waits tile t only, issued a full iter earlier), raw s_barrier pair,
//    no sched_barrier. Combines round-8's co-residency with the counted wait.
//  * attn unchanged from round 14 (8-wave split-s groups, 59.3us).

#define T_DIM 2048
#define H_DIM 16
#define SCALE_F 0.07216878364870322f   // 192^-0.5
#define EPS_F 1e-6f
#define NEG_INF (-3.402823466e38f)

typedef __attribute__((ext_vector_type(8))) short short8;
typedef __attribute__((ext_vector_type(4))) float f32x4;
typedef __attribute__((address_space(3))) char lds_char;
typedef const __attribute__((address_space(1))) char glb_char;

__device__ inline void st_out(float* p, float v) { *p = v; }
__device__ inline void st_out(__hip_bfloat16* p, float v) { *p = __float2bfloat16(v); }

// ---------------- generic f32 -> bf16 cast ----------------------------------
__global__ void cast_bf16_kernel(const float* __restrict__ src,
                                 __hip_bfloat16* __restrict__ dst,
                                 int n4_src, int n4_dst) {
    int i = blockIdx.x * 256 + threadIdx.x;
    if (i >= n4_dst) return;
    float4 v = make_float4(0.f, 0.f, 0.f, 0.f);
    if (i < n4_src) v = ((const float4*)src)[i];
    dst[4 * i + 0] = __float2bfloat16(v.x);
    dst[4 * i + 1] = __float2bfloat16(v.y);
    dst[4 * i + 2] = __float2bfloat16(v.z);
    dst[4 * i + 3] = __float2bfloat16(v.w);
}

// ---------------- megacast: x, wq_a+wkv_a(pad)->A1, wq_b->A2, biases --------
__global__ void megacast_kernel(const float* __restrict__ x,
                                const float* __restrict__ wq_a,
                                const float* __restrict__ wkv_a,
                                const float* __restrict__ wq_b,
                                const float* __restrict__ bq_a,
                                const float* __restrict__ bkv_a,
                                __hip_bfloat16* __restrict__ x_bf,
                                __hip_bfloat16* __restrict__ A1,
                                __hip_bfloat16* __restrict__ A2,
                                float* __restrict__ bias_ab) {
    const int i = blockIdx.x * 256 + threadIdx.x;
    float4 v = make_float4(0.f, 0.f, 0.f, 0.f);
    __hip_bfloat16* dst;
    if (i < 1048576) {
        v = ((const float4*)x)[i];            dst = x_bf + 4 * (size_t)i;
    } else if (i < 1835008) {
        int k = i - 1048576;
        v = ((const float4*)wq_a)[k];         dst = A1 + 4 * (size_t)k;
    } else if (i < 2162688) {
        int k = i - 1835008;
        if (k < 294912) v = ((const float4*)wkv_a)[k];
        dst = A1 + (size_t)(786432 + k) * 4;
    } else if (i < 3342336) {
        int k = i - 2162688;
        v = ((const float4*)wq_b)[k];         dst = A2 + 4 * (size_t)k;
    } else if (i < 3342880) {
        int k = i - 3342336;                  // bias granule
        float4 b = make_float4(0.f, 0.f, 0.f, 0.f);
        if (k < 384) b = ((const float4*)bq_a)[k];
        else if (k < 528) b = ((const float4*)bkv_a)[k - 384];
        ((float4*)bias_ab)[k] = b;
        return;
    } else return;
    dst[0] = __float2bfloat16(v.x);
    dst[1] = __float2bfloat16(v.y);
    dst[2] = __float2bfloat16(v.z);
    dst[3] = __float2bfloat16(v.w);
}

// ---------------- MFMA GEMM: C[M,N] = A[M,K] @ W[N,K]^T + bias[N] -----------
// 512 threads / 8 waves; wave = 32x64 quadrant; BK=64. 2-buffer counted
// pipeline: iter t stages tile t+1 into buf^1, waits vmcnt(4) (= tile t's
// loads, issued at iter t-1), s_barrier, ds_read+MFMA on buf, s_barrier.
// LDS 64KB -> 2 blocks/CU co-residency preserved. Source-preswizzled
// global_load_lds + XOR ds_read (rule #21); bijective XCD remap.
template <typename OT, bool ROPE>
__global__ __launch_bounds__(512) void gemm_mfma_kernel(
    const __hip_bfloat16* __restrict__ A, int lda,
    const __hip_bfloat16* __restrict__ W, int ldw,
    const float* __restrict__ bias,
    OT* __restrict__ C, int ldc,
    float* __restrict__ C2, int ldc2, int splitN, int K,
    const float* __restrict__ freqs) {
    __shared__ __hip_bfloat16 As[2][128 * 64];
    __shared__ __hip_bfloat16 Bs[2][128 * 64];
    const int tid = threadIdx.x;
    const int w = tid >> 6, lane = tid & 63, qd = lane >> 4, lx = lane & 15;

    // bijective XCD remap (m204)
    const int nwg = gridDim.x * gridDim.y;
    const int o = blockIdx.y * gridDim.x + blockIdx.x;
    const int qx = nwg >> 3, rx = nwg & 7;
    const int xcd = o & 7, idx = o >> 3;
    const int neu = (xcd < rx ? xcd * (qx + 1) : rx * (qx + 1) + (xcd - rx) * qx) + idx;
    const int rowB = (neu / gridDim.x) * 128, colB = (neu % gridDim.x) * 128;

    const int wr = (w >> 1) * 32, wc = (w & 1) * 64;

    f32x4 acc[2][4];
#pragma unroll
    for (int i = 0; i < 2; ++i)
#pragma unroll
        for (int j = 0; j < 4; ++j) acc[i][j] = (f32x4)(0.f);

    auto stage = [&](int buf, int k0) {
#pragma unroll
        for (int it = 0; it < 2; ++it) {
            const int g = tid + it * 512;              // 0..1023 granules
            const int row = g >> 3, s = g & 7;
            const int sc = (s ^ (row & 7)) * 8;        // pre-swizzled src col
            const __hip_bfloat16* ga = A + (size_t)(rowB + row) * lda + k0 + sc;
            __builtin_amdgcn_global_load_lds((glb_char*)ga,
                (lds_char*)((char*)&As[buf][0] + (size_t)g * 16), 16, 0, 0);
            const __hip_bfloat16* gb = W + (size_t)(colB + row) * ldw + k0 + sc;
            __builtin_amdgcn_global_load_lds((glb_char*)gb,
                (lds_char*)((char*)&Bs[buf][0] + (size_t)g * 16), 16, 0, 0);
        }
    };

    const int NT = K >> 6;            // K/64; >= 8 for all our shapes
    stage(0, 0);
    const int swz = (lx & 7) << 4;
    int cur = 0;
    for (int t = 0; t < NT; ++t) {
        // stage t+1 into buf^1 (its iter t-1 readers are behind barrier-2),
        // then wait ONLY for tile t's loads (issued a full iteration ago).
        if (t + 1 < NT) {
            stage(cur ^ 1, (t + 1) * 64);
            asm volatile("s_waitcnt vmcnt(4)" ::: "memory");
        } else {
            asm volatile("s_waitcnt vmcnt(0)" ::: "memory");
        }
        __builtin_amdgcn_s_barrier();          // tile t visible to all waves

#pragma unroll
        for (int kk = 0; kk < 2; ++kk) {
            short8 a[2], b[4];
#pragma unroll
            for (int rt = 0; rt < 2; ++rt)
                a[rt] = *(const short8*)((char*)&As[cur][0]
                    + (size_t)(wr + rt * 16 + lx) * 128 + ((kk * 64 + qd * 16) ^ swz));
#pragma unroll
            for (int ct = 0; ct < 4; ++ct)
                b[ct] = *(const short8*)((char*)&Bs[cur][0]
                    + (size_t)(wc + ct * 16 + lx) * 128 + ((kk * 64 + qd * 16) ^ swz));
#pragma unroll
            for (int rt = 0; rt < 2; ++rt)
#pragma unroll
                for (int ct = 0; ct < 4; ++ct)
                    acc[rt][ct] = __builtin_amdgcn_mfma_f32_16x16x32_bf16(a[rt], b[ct], acc[rt][ct], 0, 0, 0);
        }
        __builtin_amdgcn_s_barrier();          // readers done: buf[cur] free for t+2
        cur ^= 1;
    }

    // epilogue: C/D layout col=lane&15, row=4*qd+reg
    const bool second = (C2 != nullptr) && (colB >= splitN);
#pragma unroll
    for (int rt = 0; rt < 2; ++rt)
#pragma unroll
        for (int j = 0; j < 4; ++j) {
            const int row = rowB + wr + rt * 16 + 4 * qd + j;
#pragma unroll
            for (int ct = 0; ct < 4; ++ct) {
                const int col = colB + wc + ct * 16 + lx;
                float v = acc[rt][ct][j] + bias[col];
                if constexpr (ROPE) {
                    const float pv = __shfl_xor(v, 1);   // partner col (col^1)
                    const int dm = col % 192;
                    if (dm >= 128) {
                        const int ii = (dm - 128) >> 1;
                        const float f = freqs[row * 32 + ii];
                        const float cc = cosf(f), ss = sinf(f);
                        v = (lane & 1) ? (pv * ss + v * cc)
                                       : (v * cc - pv * ss);
                    }
                }
                if (second) C2[(size_t)row * ldc2 + (col - splitN)] = v;
                else        st_out(&C[(size_t)row * ldc + col], v);
            }
        }
}

// ---------------- RMSNorm: f32 in -> bf16 out -------------------------------
__global__ void rmsnorm_kernel(const float* __restrict__ in, __hip_bfloat16* __restrict__ outp,
                               const float* __restrict__ w,
                               int D, int in_stride, int out_stride) {
    const int row = blockIdx.x;
    const float* p = in + (size_t)row * in_stride;
    __hip_bfloat16* o = outp + (size_t)row * out_stride;
    const int tid = threadIdx.x;  // 256
    float ss = 0.f;
    for (int i = tid; i < D; i += 256) { float v = p[i]; ss += v * v; }
    __shared__ float red[256];
    red[tid] = ss;
    __syncthreads();
    for (int off = 128; off > 0; off >>= 1) {
        if (tid < off) red[tid] += red[tid + off];
        __syncthreads();
    }
    const float scale = rsqrtf(red[0] / (float)D + EPS_F);
    for (int i = tid; i < D; i += 256)
        o[i] = __float2bfloat16(p[i] * scale * w[i]);
}

// ---------------- fused rmsnorm(kv_lat) + rope(k_pe) per row ----------------
__global__ void rmsnorm_rope_kv_kernel(const float* __restrict__ kvpe,
                                       __hip_bfloat16* __restrict__ kv_lat_bf,
                                       const float* __restrict__ w,
                                       const float* __restrict__ freqs,
                                       __hip_bfloat16* __restrict__ kpe) {
    const int row = blockIdx.x;
    const float* p = kvpe + (size_t)row * 640;
    const int tid = threadIdx.x;  // 256
    float v0 = p[tid], v1 = p[tid + 256];
    __shared__ float red[256];
    red[tid] = v0 * v0 + v1 * v1;
    __syncthreads();
    for (int off = 128; off > 0; off >>= 1) {
        if (tid < off) red[tid] += red[tid + off];
        __syncthreads();
    }
    const float scale = rsqrtf(red[0] / 512.f + EPS_F);
    __hip_bfloat16* o = kv_lat_bf + (size_t)row * 512;
    o[tid]       = __float2bfloat16(v0 * scale * w[tid]);
    o[tid + 256] = __float2bfloat16(v1 * scale * w[tid + 256]);
    if (tid < 32) {
        const float f = freqs[row * 32 + tid];
        const float c = cosf(f), s = sinf(f);
        const float xr = p[512 + 2 * tid], xi = p[512 + 2 * tid + 1];
        kpe[(size_t)row * 64 + 2 * tid]     = __float2bfloat16(xr * c - xi * s);
        kpe[(size_t)row * 64 + 2 * tid + 1] = __float2bfloat16(xr * s + xi * c);
    }
}

// ---------------- pack V transposed: kvb_bf (T,H*256) -> vT (H,128,T) -------
__global__ void pack_vT_kernel(const __hip_bfloat16* __restrict__ kvb,
                               __hip_bfloat16* __restrict__ vT) {
    const int t0 = blockIdx.x * 64;
    const int h = blockIdx.y;
    const int tid = threadIdx.x;
    __shared__ __hip_bfloat16 Ls[64][136];
#pragma unroll
    for (int it = 0; it < 4; ++it) {
        int c = tid + 256 * it;
        int i = c >> 4, part = c & 15;
        *(uint4*)&Ls[i][part * 8] =
            *(const uint4*)(kvb + (size_t)(t0 + i) * 4096 + h * 256 + 128 + part * 8);
    }
    __syncthreads();
#pragma unroll
    for (int it = 0; it < 32; ++it) {
        int c = tid + 256 * it;
        int d = c >> 6, i = c & 63;
        vT[((size_t)(h * 128 + d)) * 2048 + t0 + i] = Ls[i][d];
    }
}

// ---------------- MFMA flash attention: 8-wave split-s groups ---------------
// (unchanged from round 14: 59.3us measured)
__global__ __launch_bounds__(512) void attn_mfma_kernel(
    const __hip_bfloat16* __restrict__ q,
    const __hip_bfloat16* __restrict__ kv,
    const __hip_bfloat16* __restrict__ kpe,
    const __hip_bfloat16* __restrict__ vT,
    __hip_bfloat16* __restrict__ y) {
    const int o = blockIdx.x;             // 512 = 8 XCD * 64
    const int xcd = o & 7, slot = o >> 3;
    const int h  = xcd * 2 + (slot & 1);  // each XCD owns 2 heads
    const int qt = 31 - (slot >> 1);      // longest blocks first
    const int q0 = qt * 64;
    const int NT2 = (qt >> 1) + 1;        // pairs of 64-key tiles
    const int tid = threadIdx.x;
    const int w = tid >> 6, g = w >> 2, wl = w & 3;
    const int lane = tid & 63, qd = lane >> 4, lx = lane & 15;
    const int stid = tid & 255;           // staging id within group

    __shared__ __hip_bfloat16 KsB[2][64 * 192];   // per-group; 384B rows
    __shared__ __hip_bfloat16 VsB[2][128 * 64];   // per-group; 128B rows
    __shared__ __hip_bfloat16 Ps[8][16][72];

#define KS_ADDR(gg, row, boff) ((char*)&KsB[gg][0] + (size_t)(row) * 384 + ((boff) ^ (((row) & 7) << 4)))
#define VS_ADDR(gg, row, boff) ((char*)&VsB[gg][0] + (size_t)(row) * 128 + ((boff) ^ (((row) & 7) << 4)))

    short8 qf[6];
    {
        const __hip_bfloat16* qrow =
            q + (size_t)(q0 + 16 * wl + lx) * 3072 + h * 192 + qd * 8;
#pragma unroll
        for (int kc = 0; kc < 6; ++kc)
            qf[kc] = *(const short8*)(qrow + kc * 32);
    }

    f32x4 O[8];
#pragma unroll
    for (int i = 0; i < 8; ++i) O[i] = (f32x4)(0.f);
    float mrow[4], lrow[4];
#pragma unroll
    for (int j = 0; j < 4; ++j) { mrow[j] = NEG_INF; lrow[j] = 0.f; }

    const short8 vone = (short8)(short)0x3F80;   // bf16 1.0 splat

    // ---- prefetch state: 10 NAMED uint4 per thread (group-local tile) ----
    uint4 k0r, k1r, k2r, k3r, pe0r, pe1r, v0r, v1r, v2r, v3r;
    const __hip_bfloat16* kvh = kv + h * 256;
    const __hip_bfloat16* vTh = vT + (size_t)h * 128 * 2048;

#define PREFETCH(S0)                                                               \
    do {                                                                           \
        const size_t kk_ = (size_t)(S0) + (stid >> 4);                             \
        const int kp_ = (stid & 15) * 8;                                           \
        k0r = *(const uint4*)(kvh + (kk_ +  0) * 4096 + kp_);                      \
        k1r = *(const uint4*)(kvh + (kk_ + 16) * 4096 + kp_);                      \
        k2r = *(const uint4*)(kvh + (kk_ + 32) * 4096 + kp_);                      \
        k3r = *(const uint4*)(kvh + (kk_ + 48) * 4096 + kp_);                      \
        const size_t pk_ = (size_t)(S0) + (stid >> 3);                             \
        const int pp_ = (stid & 7) * 8;                                            \
        pe0r = *(const uint4*)(kpe + (pk_ +  0) * 64 + pp_);                       \
        pe1r = *(const uint4*)(kpe + (pk_ + 32) * 64 + pp_);                       \
        const __hip_bfloat16* vp_ = vTh + ((size_t)(stid >> 3)) * 2048 + (S0) + pp_;\
        v0r = *(const uint4*)(vp_ + 0 * 65536);                                    \
        v1r = *(const uint4*)(vp_ + 1 * 65536);                                    \
        v2r = *(const uint4*)(vp_ + 2 * 65536);                                    \
        v3r = *(const uint4*)(vp_ + 3 * 65536);                                    \
    } while (0)

// one 64-key online-softmax + PV pass over group buffer GG, keys at S0P
#define COMPUTE64(S0P, GG)                                                         \
    do {                                                                           \
        f32x4 S[4];                                                                \
        _Pragma("unroll")                                                          \
        for (int nt = 0; nt < 4; ++nt) S[nt] = (f32x4)(0.f);                       \
        __builtin_amdgcn_s_setprio(1);                                             \
        _Pragma("unroll")                                                          \
        for (int kc = 0; kc < 6; ++kc) {                                           \
            short8 a = qf[kc];                                                     \
            _Pragma("unroll")                                                      \
            for (int nt = 0; nt < 4; ++nt) {                                       \
                short8 b = *(const short8*)KS_ADDR(GG, nt * 16 + lx,               \
                                                   kc * 64 + qd * 16);             \
                S[nt] = __builtin_amdgcn_mfma_f32_16x16x32_bf16(a, b, S[nt], 0, 0, 0); \
            }                                                                      \
        }                                                                          \
        __builtin_amdgcn_s_setprio(0);                                             \
        float sv[4][4];                                                            \
        _Pragma("unroll")                                                          \
        for (int nt = 0; nt < 4; ++nt) {                                           \
            int col = (S0P) + nt * 16 + lx;                                        \
            _Pragma("unroll")                                                      \
            for (int j = 0; j < 4; ++j) {                                          \
                int row = q0 + 16 * wl + 4 * qd + j;                               \
                float v = S[nt][j] * SCALE_F;                                      \
                sv[nt][j] = (col > row) ? NEG_INF : v;                             \
            }                                                                      \
        }                                                                          \
        float pmax[4];                                                             \
        _Pragma("unroll")                                                          \
        for (int j = 0; j < 4; ++j)                                                \
            pmax[j] = fmaxf(fmaxf(sv[0][j], sv[1][j]), fmaxf(sv[2][j], sv[3][j])); \
        const bool need = !__all((pmax[0] <= mrow[0] + 8.f) &&                     \
                                 (pmax[1] <= mrow[1] + 8.f) &&                     \
                                 (pmax[2] <= mrow[2] + 8.f) &&                     \
                                 (pmax[3] <= mrow[3] + 8.f));                      \
        if (need) {                                                                \
            float al[4];                                                           \
            _Pragma("unroll")                                                      \
            for (int j = 0; j < 4; ++j) {                                          \
                float rm = pmax[j];                                                \
                _Pragma("unroll")                                                  \
                for (int msk = 1; msk < 16; msk <<= 1)                             \
                    rm = fmaxf(rm, __shfl_xor(rm, msk));                           \
                const float mn = fmaxf(mrow[j], rm);                               \
                al[j] = __expf(mrow[j] - mn);                                      \
                mrow[j] = mn;                                                      \
                lrow[j] *= al[j];                                                  \
            }                                                                      \
            _Pragma("unroll")                                                      \
            for (int nt = 0; nt < 8; ++nt)                                         \
                _Pragma("unroll")                                                  \
                for (int j = 0; j < 4; ++j) O[nt][j] *= al[j];                     \
        }                                                                          \
        _Pragma("unroll")                                                          \
        for (int nt = 0; nt < 4; ++nt)                                             \
            _Pragma("unroll")                                                      \
            for (int j = 0; j < 4; ++j) {                                          \
                float pp = __expf(sv[nt][j] - mrow[j]);                            \
                Ps[w][4 * qd + j][nt * 16 + lx] = __float2bfloat16(pp);            \
            }                                                                      \
        asm volatile("s_waitcnt lgkmcnt(0)" ::: "memory");                         \
        f32x4 lacc = (f32x4)(0.f);                                                 \
        __builtin_amdgcn_s_setprio(1);                                             \
        _Pragma("unroll")                                                          \
        for (int kc2 = 0; kc2 < 2; ++kc2) {                                        \
            short8 pa = *(const short8*)&Ps[w][lx][kc2 * 32 + qd * 8];             \
            _Pragma("unroll")                                                      \
            for (int nt = 0; nt < 8; ++nt) {                                       \
                short8 vb = *(const short8*)VS_ADDR(GG, nt * 16 + lx,              \
                                                    kc2 * 64 + qd * 16);           \
                O[nt] = __builtin_amdgcn_mfma_f32_16x16x32_bf16(pa, vb, O[nt], 0, 0, 0); \
            }                                                                      \
            lacc = __builtin_amdgcn_mfma_f32_16x16x32_bf16(pa, vone, lacc, 0, 0, 0); \
        }                                                                          \
        __builtin_amdgcn_s_setprio(0);                                             \
        _Pragma("unroll")                                                          \
        for (int j = 0; j < 4; ++j) lrow[j] += lacc[j];                            \
    } while (0)

    if (g <= qt) PREFETCH(g * 64);

    for (int t2 = 0; t2 < NT2; ++t2) {
        const int t = 2 * t2 + g;
        const bool act = (t <= qt);        // group-uniform (wave-uniform)
        __syncthreads();   // all waves done reading their group buffer
        if (act) {
            const int kr_ = stid >> 4, kb_ = (stid & 15) * 16;
            *(uint4*)KS_ADDR(g, kr_ +  0, kb_) = k0r;
            *(uint4*)KS_ADDR(g, kr_ + 16, kb_) = k1r;
            *(uint4*)KS_ADDR(g, kr_ + 32, kb_) = k2r;
            *(uint4*)KS_ADDR(g, kr_ + 48, kb_) = k3r;
            const int pr_ = stid >> 3, pb_ = (stid & 7) * 16;
            *(uint4*)KS_ADDR(g, pr_ +  0, 256 + pb_) = pe0r;
            *(uint4*)KS_ADDR(g, pr_ + 32, 256 + pb_) = pe1r;
            *(uint4*)VS_ADDR(g, pr_ +  0, pb_) = v0r;
            *(uint4*)VS_ADDR(g, pr_ + 32, pb_) = v1r;
            *(uint4*)VS_ADDR(g, pr_ + 64, pb_) = v2r;
            *(uint4*)VS_ADDR(g, pr_ + 96, pb_) = v3r;
        }
        __syncthreads();   // tiles visible

        const int tn = 2 * (t2 + 1) + g;
        if (tn <= qt) PREFETCH(tn * 64);   // latency hides under compute

        if (act) COMPUTE64(t * 64, g);
    }
#undef PREFETCH
#undef COMPUTE64
#undef KS_ADDR
#undef VS_ADDR

    // ---- merge group 1 state into group 0, write y ----
    float* Osh = (float*)&KsB[0][0];       // 64 x 128 f32 (32 KB <= 48 KB)
    float* msh = (float*)&VsB[0][0];       // 64
    float* lsh = msh + 64;
    __syncthreads();                       // group 0 done reading LDS
    if (g == 1) {
#pragma unroll
        for (int j = 0; j < 4; ++j) {
            const int r = 16 * wl + 4 * qd + j;
            if (lx == 0) { msh[r] = mrow[j]; lsh[r] = lrow[j]; }
#pragma unroll
            for (int nt = 0; nt < 8; ++nt)
                Osh[r * 128 + nt * 16 + lx] = O[nt][j];
        }
    }
    __syncthreads();
    if (g == 0) {
#pragma unroll
        for (int j = 0; j < 4; ++j) {
            const int r = 16 * wl + 4 * qd + j;
            const float m1 = msh[r], l1 = lsh[r];
            const float M  = fmaxf(mrow[j], m1);
            const float a0 = __expf(mrow[j] - M);
            const float a1 = __expf(m1 - M);        // 0 when group 1 idle
            const float inv = 1.f / (lrow[j] * a0 + l1 * a1);
            const int t = q0 + r;
            __hip_bfloat16* yr = y + (size_t)t * 2048 + h * 128 + lx;
#pragma unroll
            for (int nt = 0; nt < 8; ++nt)
                yr[nt * 16] = __float2bfloat16(
                    (O[nt][j] * a0 + Osh[r * 128 + nt * 16 + lx] * a1) * inv);
        }
    }
}

extern "C" void kernel_launch(void* const* d_in, const int* in_sizes, int n_in,
                              void* d_out, int out_size, void* d_ws, size_t ws_size,
                              hipStream_t stream) {
    const float* x         = (const float*)d_in[0];
    const float* freqs     = (const float*)d_in[1];
    const float* wq_a      = (const float*)d_in[2];
    const float* bq_a      = (const float*)d_in[3];
    const float* q_norm_w  = (const float*)d_in[4];
    const float* wq_b      = (const float*)d_in[5];
    const float* bq_b      = (const float*)d_in[6];
    const float* wkv_a     = (const float*)d_in[7];
    const float* bkv_a     = (const float*)d_in[8];
    const float* kv_norm_w = (const float*)d_in[9];
    const float* wkv_b     = (const float*)d_in[10];
    const float* bkv_b     = (const float*)d_in[11];
    const float* wo        = (const float*)d_in[12];
    const float* bo        = (const float*)d_in[13];
    float* out = (float*)d_out;

    // Workspace layout (~74 MB).
    char* p = (char*)d_ws;
    float* q_lat = (float*)p;                        p += (size_t)2048 * 1536 * 4;  // later hosts yb_bf
    float* kvpe  = (float*)p;                        p += (size_t)2048 * 640 * 4;
    __hip_bfloat16* x_bf      = (__hip_bfloat16*)p;  p += (size_t)2048 * 2048 * 2;  // later hosts vT
    __hip_bfloat16* q_lat_bf  = (__hip_bfloat16*)p;  p += (size_t)2048 * 1536 * 2;
    __hip_bfloat16* qb_bf     = (__hip_bfloat16*)p;  p += (size_t)2048 * 3072 * 2;
    __hip_bfloat16* kv_lat_bf = (__hip_bfloat16*)p;  p += (size_t)2048 * 512 * 2;
    __hip_bfloat16* kvb_bf    = (__hip_bfloat16*)p;  p += (size_t)2048 * 4096 * 2;
    __hip_bfloat16* kpe_bf    = (__hip_bfloat16*)p;  p += (size_t)2048 * 64 * 2;
    __hip_bfloat16* A1        = (__hip_bfloat16*)p;  p += (size_t)3072 * 1536 * 2;  // weight arena (9.44 MB)
    float* bias_ab = (float*)p;                      p += (size_t)2176 * 4;
    __hip_bfloat16* vT    = x_bf;                    // alias: x_bf dead after G12
    __hip_bfloat16* yb_bf = (__hip_bfloat16*)q_lat;  // alias: q_lat dead after rmsnorm
    __hip_bfloat16* A2    = kvb_bf;                  // alias: wq_b lives cast..G3 < G4 write

    // 1. megacast: x, wq_a+wkv_a -> A1, wq_b -> A2, fused bias
    megacast_kernel<<<13059, 256, 0, stream>>>(x, wq_a, wkv_a, wq_b, bq_a, bkv_a,
                                               x_bf, A1, A2, bias_ab);
    // 2. GEMM 1+2 fused: [q_lat | kvpe] = x_bf @ A1^T + bias
    gemm_mfma_kernel<float, false><<<dim3(17, 16), 512, 0, stream>>>(
        x_bf, 2048, A1, 2048, bias_ab, q_lat, 1536, kvpe, 640, 1536, 2048, nullptr);
    // 3. wkv_b -> A1 (A1 free after G12)
    cast_bf16_kernel<<<2048, 256, 0, stream>>>(wkv_b, A1, 524288, 524288);
    // 4. rmsnorm q -> bf16
    rmsnorm_kernel<<<2048, 256, 0, stream>>>(q_lat, q_lat_bf, q_norm_w, 1536, 1536, 1536);
    // 5. GEMM 3 + fused rope_q: qb_bf = q_lat_bf @ wq_b^T + bq_b
    gemm_mfma_kernel<__hip_bfloat16, true><<<dim3(24, 16), 512, 0, stream>>>(
        q_lat_bf, 1536, A2, 1536, bq_b, qb_bf, 3072, nullptr, 0, 1 << 30, 1536, freqs);
    // 6. fused rmsnorm(kv) + rope(k_pe)
    rmsnorm_rope_kv_kernel<<<2048, 256, 0, stream>>>(kvpe, kv_lat_bf, kv_norm_w, freqs, kpe_bf);
    // 7. GEMM 4: kvb_bf = kv_lat_bf @ wkv_b^T + bkv_b
    gemm_mfma_kernel<__hip_bfloat16, false><<<dim3(32, 16), 512, 0, stream>>>(
        kv_lat_bf, 512, A1, 512, bkv_b, kvb_bf, 4096, nullptr, 0, 1 << 30, 512, nullptr);
    // 8. wo -> A1 (A1 free after G4)
    cast_bf16_kernel<<<4096, 256, 0, stream>>>(wo, A1, 1048576, 1048576);
    // 9. pack V^T
    pack_vT_kernel<<<dim3(32, 16), 256, 0, stream>>>(kvb_bf, vT);
    // 10. attention (512 threads: 2 split-s wave groups)
    attn_mfma_kernel<<<512, 512, 0, stream>>>(qb_bf, kvb_bf, kpe_bf, vT, yb_bf);
    // 11. GEMM 5: out = yb_bf @ wo^T + bo
    gemm_mfma_kernel<float, false><<<dim3(16, 16), 512, 0, stream>>>(
        yb_bf, 2048, A1, 2048, bo, out, 2048, nullptr, 0, 1 << 30, 2048, nullptr);
}